// Round 12
// baseline (83.109 us; speedup 1.0000x reference)
//
#include <hip/hip_runtime.h>
#include <hip/hip_bf16.h>
#include <math.h>

// PhaseMLP fused, R15: R14 + B register pipeline deepened 3 -> 4.
//   y[b,o] = sum_k c_k(b) * ( x[b,:] @ W_k + b_k )
// R14 post-mortem: removing the B LDS round-trip was NULL vs R13 -> the
// limiter is the VMEM request path common to both (effective ~23 B/cy/CU,
// 37% of L2 ceiling -> NOT the BW roofline). Model: in-order per-wave issue
// couples latency to pipeline depth (stall ~ L/depth per iteration;
// L~500cy). Depth is the unprobed axis; 4 is the max fitting 4 waves/SIMD
// (pre[4][4]=64 VGPR + 16 acc + misc <= 128, forced by launch_bounds).
// Single variable vs R14: prologue stages chunks 0..3; step s consumes
// slot s&3, issues chunk s+4 (tail guards fold). Consumption order 0..15
// identical -> same accumulation, absmax unchanged.

typedef __attribute__((ext_vector_type(8))) short bf16x8;
typedef __attribute__((ext_vector_type(4))) float f32x4;

// LDS layout (bytes) for k_fused
#define LDS_A0  0                   // 16 rows x 256B = 4096
#define LDS_A1  4096                // 16 rows x 512B = 8192
#define LDS_A2  12288               // 16 rows x 512B = 8192
#define LDS_CB  20480               // 16 x float4    = 256
#define LDS_RED 20736               // [8][16][17] fp32 = 8704
#define LDS_TOT (20736 + 8704)      // 29440

static __device__ __forceinline__ void bar_lgkm() {
  asm volatile("s_waitcnt lgkmcnt(0)" ::: "memory");
  __builtin_amdgcn_s_barrier();
  asm volatile("" ::: "memory");
}

static __device__ __forceinline__ unsigned short f2bf(float f) {
  union { float f; unsigned int u; } v; v.f = f;
  unsigned int r = v.u + 0x7fffu + ((v.u >> 16) & 1u);  // RNE
  return (unsigned short)(r >> 16);
}

// Catmull-Rom basis coeffs in ABSOLUTE anchor order (c[0..3] for anchors 0..3)
static __device__ __forceinline__ void catmull(float ph, float c[4]) {
  float t = 4.0f * ph;
  float ft = floorf(t);
  int i1 = ((int)ft) & 3;
  float w = t - ft;
  float w2 = w * w, w3 = w2 * w;
  float r0 = -0.5f * w + w2 - 0.5f * w3;
  float r1 = 1.0f - 2.5f * w2 + 1.5f * w3;
  float r2 = 0.5f * w + 2.0f * w2 - 1.5f * w3;
  float r3 = -0.5f * w2 + 0.5f * w3;
  c[(i1 + 3) & 3] = r0;
  c[i1]           = r1;
  c[(i1 + 1) & 3] = r2;
  c[(i1 + 2) & 3] = r3;
}

// ---------------------------------------------------------------------------
// Pack v2 (coalesced, unchanged from R13): W fp32 [4][K][O] -> bf16 packed
// LDS-image layout; granule w = MFMA B-fragment of lane w (col=w&15,q=w>>4).
// ---------------------------------------------------------------------------
#define TPAD 66
__global__ __launch_bounds__(256) void k_pack(
    const float* __restrict__ w0, const float* __restrict__ w1,
    const float* __restrict__ w2, unsigned short* __restrict__ t0,
    unsigned short* __restrict__ t1, unsigned short* __restrict__ t2) {
  __shared__ float tile[4 * 32 * TPAD];   // 33792 B
  const int u = blockIdx.x;
  const int t = threadIdx.x;

  const float* W; unsigned short* T;
  int q, ci8, KO, Ostr, nsub, cgmul, cisub;
  if (u < 16) {            // layer 0
    q = u >> 2; ci8 = u & 3;
    W = w0; T = t0; KO = 128 * 256; Ostr = 256; nsub = 4;
    cgmul = 8192; cisub = ci8;
  } else if (u < 48) {     // layer 1
    const int uu = u - 16; q = uu >> 3; ci8 = uu & 7;
    W = w1; T = t1; KO = 256 * 256; Ostr = 256; nsub = 4;
    cgmul = 16384; cisub = ci8;
  } else {                 // layer 2
    const int uu = u - 48; q = uu >> 3; ci8 = uu & 7;
    W = w2; T = t2; KO = 256 * 128; Ostr = 128; nsub = 4;
    cgmul = 16384; cisub = ci8;
  }
  const int kbase = ci8 * 32;
  const int obase = q * 64;

  // ---- phase 1: coalesced load, 8 x float4 per thread ----
#pragma unroll
  for (int p = 0; p < 8; ++p) {
    const int f4 = p * 256 + t;              // 0..2047
    const int a = f4 >> 9;                   // 0..3
    const int k = (f4 >> 4) & 31;            // 0..31
    const int o4 = f4 & 15;                  // 0..15
    const float4 v = *(const float4*)(W + (size_t)a * KO +
                                      (size_t)(kbase + k) * Ostr + obase + o4 * 4);
    float* d = tile + a * (32 * TPAD) + k * TPAD + o4 * 4;
    d[0] = v.x; d[1] = v.y; d[2] = v.z; d[3] = v.w;
  }
  __syncthreads();

  // ---- phase 2: gather + convert + contiguous granule writes ----
  const int a = t >> 6, w = t & 63, col = w & 15, quad = w >> 4;
#pragma unroll
  for (int s = 0; s < nsub; ++s) {
    const float* src = tile + a * (32 * TPAD) + (quad * 8) * TPAD + s * 16 + col;
    bf16x8 v;
#pragma unroll
    for (int j = 0; j < 8; ++j) v[j] = (short)f2bf(src[j * TPAD]);
    size_t dst;
    if (u < 48) {
      dst = (size_t)(q * 4 + s) * (size_t)cgmul + (size_t)cisub * 2048 + a * 512 + w * 8;
    } else {
      const int cg = q * 4 + s, kh = ci8 >> 2, ci4 = ci8 & 3;
      dst = (size_t)(cg * 2 + kh) * 8192 + (size_t)ci4 * 2048 + a * 512 + w * 8;
    }
    *(bf16x8*)(T + dst) = v;
  }
}

// mid-layer epilogue: bias-mix, ELU, one bf16 write per (row,col)
static __device__ __forceinline__ void epi_mid(f32x4 a0, f32x4 a1, f32x4 a2, f32x4 a3,
                                               const float bv[4], const float* cbf,
                                               int colg, int quad, char* outBuf) {
  const int g = colg >> 3;
  const int j2 = (colg & 7) * 2;
#pragma unroll
  for (int r = 0; r < 4; ++r) {
    const int m = quad * 4 + r;
    const float4 c = *(const float4*)(cbf + m * 4);
    float y = c.x * (a0[r] + bv[0]) + c.y * (a1[r] + bv[1]) +
              c.z * (a2[r] + bv[2]) + c.w * (a3[r] + bv[3]);
    float a = y > 0.0f ? y : (__expf(y) - 1.0f);  // ELU
    *(unsigned short*)(outBuf + m * 512 + (((g ^ (m & 15)) << 4) + j2)) = f2bf(a);
  }
}

// load one packed K=32 chunk (4 anchors x 1KB contiguous) into rotating slot.
// sb already includes lane*8 shorts; wave-level each load = 1KB linear.
#define LOADCH(sb, ci, sl) do {                                        \
    pre[sl][0] = *(const bf16x8*)((sb) + (ci) * 2048);                 \
    pre[sl][1] = *(const bf16x8*)((sb) + (ci) * 2048 + 512);           \
    pre[sl][2] = *(const bf16x8*)((sb) + (ci) * 2048 + 1024);          \
    pre[sl][3] = *(const bf16x8*)((sb) + (ci) * 2048 + 1536);          \
  } while (0)

// global chunk id c: 0..3 = L0, 4..11 = L1, 12..15 = L2; c>=16 folds to nop
#define ISSUE(c, sl) do {                                              \
    if ((c) < 4)       LOADCH(sb0, (c), sl);                           \
    else if ((c) < 12) LOADCH(sb1, (c) - 4, sl);                       \
    else if ((c) < 16) LOADCH(sb2, (c) - 12, sl);                      \
  } while (0)

#define MFMA4()                                                            \
  acc0 = __builtin_amdgcn_mfma_f32_16x16x32_bf16(av, bv0, acc0, 0, 0, 0);  \
  acc1 = __builtin_amdgcn_mfma_f32_16x16x32_bf16(av, bv1, acc1, 0, 0, 0);  \
  acc2 = __builtin_amdgcn_mfma_f32_16x16x32_bf16(av, bv2, acc2, 0, 0, 0);  \
  acc3 = __builtin_amdgcn_mfma_f32_16x16x32_bf16(av, bv3, acc3, 0, 0, 0)

__global__ __launch_bounds__(1024, 4) void k_fused(
    const float* __restrict__ x, const float* __restrict__ phase,
    const unsigned short* __restrict__ Wt0, const float* __restrict__ b0,
    const unsigned short* __restrict__ Wt1, const float* __restrict__ b1,
    const unsigned short* __restrict__ Wt2, const float* __restrict__ b2,
    float* __restrict__ out) {
  __shared__ __align__(1024) char smem[LDS_TOT];

  const int tid = threadIdx.x;
  const int lane = tid & 63;
  const int wid = tid >> 6;     // 0..15
  const int col = lane & 15;    // MFMA row-of-A / col-of-B lane index
  const int quad = lane >> 4;
  const int m0 = blockIdx.x * 16;
  const int colg = wid * 16 + col;           // L0/L1 output column
  const int cg = wid & 7, kh = wid >> 3;     // L2: col-group + K-half
  const int colg2 = cg * 16 + col;
  const int hi16 = (col & 12) << 4;          // A-swizzle high bits
  const int lb = (quad ^ (col & 3)) << 4;    // A-swizzle low bits

  float* cbf = (float*)(smem + LDS_CB);

  // packed per-lane source bases (shorts): base + lane*8
  const unsigned short* sb0 = Wt0 + (size_t)wid * 8192 + lane * 8;
  const unsigned short* sb1 = Wt1 + (size_t)wid * 16384 + lane * 8;
  const unsigned short* sb2 = Wt2 + (size_t)(cg * 2 + kh) * 8192 + lane * 8;

  // ---- prologue global loads ----
  float4 xv = {0.f, 0.f, 0.f, 0.f};
  if (tid < 512)
    xv = *(const float4*)(x + (size_t)(m0 + (tid >> 5)) * 128 + (tid & 31) * 4);

  float bva[4], bvb[4], bvc[4];
#pragma unroll
  for (int k = 0; k < 4; ++k) {
    bva[k] = b0[k * 256 + colg];
    bvb[k] = b1[k * 256 + colg];
    bvc[k] = b2[k * 128 + colg2];
  }

  // ---- start the register B pipeline: chunks 0..3 -> slots 0..3 ----
  bf16x8 pre[4][4];
  LOADCH(sb0, 0, 0);
  LOADCH(sb0, 1, 1);
  LOADCH(sb0, 2, 2);
  LOADCH(sb0, 3, 3);

  // Catmull coeff table (16 rows)
  if (tid < 16) {
    float c[4];
    catmull(phase[m0 + tid], c);
    cbf[tid * 4 + 0] = c[0]; cbf[tid * 4 + 1] = c[1];
    cbf[tid * 4 + 2] = c[2]; cbf[tid * 4 + 3] = c[3];
  }

  // ---- build A0: unscaled bf16 x, granule-swizzled (g ^ (row&15)) ----
  if (tid < 512) {
    const int row = tid >> 5, seg = tid & 31;
    const int g = seg >> 1, h = seg & 1;
    short4 hv;
    hv.x = (short)f2bf(xv.x); hv.y = (short)f2bf(xv.y);
    hv.z = (short)f2bf(xv.z); hv.w = (short)f2bf(xv.w);
    *(short4*)(smem + LDS_A0 + row * 256 + ((g ^ (row & 15)) << 4) + h * 8) = hv;
  }
  bar_lgkm();

  f32x4 acc0, acc1, acc2, acc3;

  // ---- layer 0: A0 (K=128 x 4 anchors) @ Wt0 -> A1. steps s=0..3 ----
  {
    acc0 = acc1 = acc2 = acc3 = (f32x4){0.f, 0.f, 0.f, 0.f};
    const char* aL = smem + LDS_A0 + col * 256 + lb;
#pragma unroll
    for (int i = 0; i < 4; ++i) {
      const int sl = i & 3;
      bf16x8 bv0 = pre[sl][0], bv1 = pre[sl][1],
             bv2 = pre[sl][2], bv3 = pre[sl][3];
      ISSUE(i + 4, sl);
      bf16x8 av = *(const bf16x8*)(aL + ((i << 6) ^ hi16));
      MFMA4();
    }
    epi_mid(acc0, acc1, acc2, acc3, bva, cbf, colg, quad, smem + LDS_A1);
  }
  bar_lgkm();

  // ---- layer 1: A1 (K=256 x 4 anchors) @ Wt1 -> A2. steps s=4..11 ----
  {
    acc0 = acc1 = acc2 = acc3 = (f32x4){0.f, 0.f, 0.f, 0.f};
    const char* aL = smem + LDS_A1 + col * 512 + lb;
#pragma unroll
    for (int i = 0; i < 8; ++i) {
      const int s = i + 4;
      const int sl = s & 3;
      bf16x8 bv0 = pre[sl][0], bv1 = pre[sl][1],
             bv2 = pre[sl][2], bv3 = pre[sl][3];
      ISSUE(s + 4, sl);
      bf16x8 av = *(const bf16x8*)(aL + ((i << 6) ^ hi16));
      MFMA4();
    }
    epi_mid(acc0, acc1, acc2, acc3, bvb, cbf, colg, quad, smem + LDS_A2);
  }
  bar_lgkm();

  // ---- layer 2: A2 (K=256 x 4 anchors) @ Wt2 -> out. steps s=12..15 ----
  {
    acc0 = acc1 = acc2 = acc3 = (f32x4){0.f, 0.f, 0.f, 0.f};
    const char* aL = smem + LDS_A2 + col * 512 + kh * 256 + lb;
#pragma unroll
    for (int i = 0; i < 4; ++i) {
      const int s = i + 12;
      const int sl = s & 3;
      bf16x8 bv0 = pre[sl][0], bv1 = pre[sl][1],
             bv2 = pre[sl][2], bv3 = pre[sl][3];
      ISSUE(s + 4, sl);    // s+4 >= 16 -> folds to nop
      bf16x8 av = *(const bf16x8*)(aL + ((i << 6) ^ hi16));
      MFMA4();
    }

    // anchor-combine partials
    float part[4];
#pragma unroll
    for (int r = 0; r < 4; ++r) {
      const int m = quad * 4 + r;
      const float4 c = *(const float4*)(cbf + m * 4);
      part[r] = c.x * acc0[r] + c.y * acc1[r] + c.z * acc2[r] + c.w * acc3[r];
    }

    float* red = (float*)(smem + LDS_RED);   // [8][16][17]
    if (kh) {
#pragma unroll
      for (int r = 0; r < 4; ++r)
        red[cg * 272 + (quad * 4 + r) * 17 + col] = part[r];
    }
    bar_lgkm();
    if (!kh) {
#pragma unroll
      for (int r = 0; r < 4; ++r) {
        const int m = quad * 4 + r;
        const float4 c = *(const float4*)(cbf + m * 4);
        float y = part[r] + red[cg * 272 + m * 17 + col] +
                  c.x * bvc[0] + c.y * bvc[1] + c.z * bvc[2] + c.w * bvc[3];
        out[(size_t)(m0 + m) * 128 + colg2] = y;
      }
    }
  }
}

// ---------------------------------------------------------------------------
// ws layout: Wt0 @0 (256KB), Wt1 @256KB (512KB), Wt2 @768KB (256KB). 1 MB.
// ---------------------------------------------------------------------------
extern "C" void kernel_launch(void* const* d_in, const int* in_sizes, int n_in,
                              void* d_out, int out_size, void* d_ws, size_t ws_size,
                              hipStream_t stream) {
  const float* x     = (const float*)d_in[0];
  const float* phase = (const float*)d_in[1];
  const float* w0    = (const float*)d_in[2];
  const float* b0    = (const float*)d_in[3];
  const float* w1    = (const float*)d_in[4];
  const float* b1    = (const float*)d_in[5];
  const float* w2    = (const float*)d_in[6];
  const float* b2    = (const float*)d_in[7];
  float* out = (float*)d_out;

  char* ws = (char*)d_ws;
  unsigned short* Wt0 = (unsigned short*)ws;
  unsigned short* Wt1 = (unsigned short*)(ws + 262144);
  unsigned short* Wt2 = (unsigned short*)(ws + 262144 + 524288);

  k_pack<<<64, 256, 0, stream>>>(w0, w1, w2, Wt0, Wt1, Wt2);
  k_fused<<<256, 1024, 0, stream>>>(x, phase, Wt0, b0, Wt1, b1, Wt2, b2, out);
}

// Round 13
// 82.243 us; speedup vs baseline: 1.0105x; 1.0105x over previous
//
#include <hip/hip_runtime.h>
#include <hip/hip_bf16.h>
#include <math.h>

// PhaseMLP fused, R16: R14 + cooperative XCD-local L2 prefill of weights.
//   y[b,o] = sum_k c_k(b) * ( x[b,:] @ W_k + b_k )
// R14/R15 post-mortem: stream time invariant to B-destination, request
// structure, pipeline depth -> the 1MB/CU weight stream is served by L3,
// not L2: all 32 CUs of an XCD sweep the same bytes in lockstep, so every
// line is missed by all CUs before its first fill lands (no L2 reuse);
// 256 blocks x 1MB = 256MB from L3 @ ~15 TB/s ~= the observed ~20us.
// Fix: blocks round-robin XCDs (bid%8); peer p=bid>>3 pre-touches a
// DISJOINT 32KB slice of the contiguous 1MB packed image (1 dword/thread,
// stride 32B touches every 128B line) as the FIRST load; kept live via
// no-op asm after layer 0 (in-order VMEM -> wait is free there). The 32
// peers fill each XCD's L2 during the prologue (8MB total from L3), and
// the main sweep runs from local L2. Everything else = R14 (depth 3).

typedef __attribute__((ext_vector_type(8))) short bf16x8;
typedef __attribute__((ext_vector_type(4))) float f32x4;

// LDS layout (bytes) for k_fused
#define LDS_A0  0                   // 16 rows x 256B = 4096
#define LDS_A1  4096                // 16 rows x 512B = 8192
#define LDS_A2  12288               // 16 rows x 512B = 8192
#define LDS_CB  20480               // 16 x float4    = 256
#define LDS_RED 20736               // [8][16][17] fp32 = 8704
#define LDS_TOT (20736 + 8704)      // 29440

static __device__ __forceinline__ void bar_lgkm() {
  asm volatile("s_waitcnt lgkmcnt(0)" ::: "memory");
  __builtin_amdgcn_s_barrier();
  asm volatile("" ::: "memory");
}

static __device__ __forceinline__ unsigned short f2bf(float f) {
  union { float f; unsigned int u; } v; v.f = f;
  unsigned int r = v.u + 0x7fffu + ((v.u >> 16) & 1u);  // RNE
  return (unsigned short)(r >> 16);
}

// Catmull-Rom basis coeffs in ABSOLUTE anchor order (c[0..3] for anchors 0..3)
static __device__ __forceinline__ void catmull(float ph, float c[4]) {
  float t = 4.0f * ph;
  float ft = floorf(t);
  int i1 = ((int)ft) & 3;
  float w = t - ft;
  float w2 = w * w, w3 = w2 * w;
  float r0 = -0.5f * w + w2 - 0.5f * w3;
  float r1 = 1.0f - 2.5f * w2 + 1.5f * w3;
  float r2 = 0.5f * w + 2.0f * w2 - 1.5f * w3;
  float r3 = -0.5f * w2 + 0.5f * w3;
  c[(i1 + 3) & 3] = r0;
  c[i1]           = r1;
  c[(i1 + 1) & 3] = r2;
  c[(i1 + 2) & 3] = r3;
}

// ---------------------------------------------------------------------------
// Pack v2 (coalesced, unchanged from R13): W fp32 [4][K][O] -> bf16 packed
// LDS-image layout; granule w = MFMA B-fragment of lane w (col=w&15,q=w>>4).
// ---------------------------------------------------------------------------
#define TPAD 66
__global__ __launch_bounds__(256) void k_pack(
    const float* __restrict__ w0, const float* __restrict__ w1,
    const float* __restrict__ w2, unsigned short* __restrict__ t0,
    unsigned short* __restrict__ t1, unsigned short* __restrict__ t2) {
  __shared__ float tile[4 * 32 * TPAD];   // 33792 B
  const int u = blockIdx.x;
  const int t = threadIdx.x;

  const float* W; unsigned short* T;
  int q, ci8, KO, Ostr, nsub, cgmul, cisub;
  if (u < 16) {            // layer 0
    q = u >> 2; ci8 = u & 3;
    W = w0; T = t0; KO = 128 * 256; Ostr = 256; nsub = 4;
    cgmul = 8192; cisub = ci8;
  } else if (u < 48) {     // layer 1
    const int uu = u - 16; q = uu >> 3; ci8 = uu & 7;
    W = w1; T = t1; KO = 256 * 256; Ostr = 256; nsub = 4;
    cgmul = 16384; cisub = ci8;
  } else {                 // layer 2
    const int uu = u - 48; q = uu >> 3; ci8 = uu & 7;
    W = w2; T = t2; KO = 256 * 128; Ostr = 128; nsub = 4;
    cgmul = 16384; cisub = ci8;
  }
  const int kbase = ci8 * 32;
  const int obase = q * 64;

  // ---- phase 1: coalesced load, 8 x float4 per thread ----
#pragma unroll
  for (int p = 0; p < 8; ++p) {
    const int f4 = p * 256 + t;              // 0..2047
    const int a = f4 >> 9;                   // 0..3
    const int k = (f4 >> 4) & 31;            // 0..31
    const int o4 = f4 & 15;                  // 0..15
    const float4 v = *(const float4*)(W + (size_t)a * KO +
                                      (size_t)(kbase + k) * Ostr + obase + o4 * 4);
    float* d = tile + a * (32 * TPAD) + k * TPAD + o4 * 4;
    d[0] = v.x; d[1] = v.y; d[2] = v.z; d[3] = v.w;
  }
  __syncthreads();

  // ---- phase 2: gather + convert + contiguous granule writes ----
  const int a = t >> 6, w = t & 63, col = w & 15, quad = w >> 4;
#pragma unroll
  for (int s = 0; s < nsub; ++s) {
    const float* src = tile + a * (32 * TPAD) + (quad * 8) * TPAD + s * 16 + col;
    bf16x8 v;
#pragma unroll
    for (int j = 0; j < 8; ++j) v[j] = (short)f2bf(src[j * TPAD]);
    size_t dst;
    if (u < 48) {
      dst = (size_t)(q * 4 + s) * (size_t)cgmul + (size_t)cisub * 2048 + a * 512 + w * 8;
    } else {
      const int cg = q * 4 + s, kh = ci8 >> 2, ci4 = ci8 & 3;
      dst = (size_t)(cg * 2 + kh) * 8192 + (size_t)ci4 * 2048 + a * 512 + w * 8;
    }
    *(bf16x8*)(T + dst) = v;
  }
}

// mid-layer epilogue: bias-mix, ELU, one bf16 write per (row,col)
static __device__ __forceinline__ void epi_mid(f32x4 a0, f32x4 a1, f32x4 a2, f32x4 a3,
                                               const float bv[4], const float* cbf,
                                               int colg, int quad, char* outBuf) {
  const int g = colg >> 3;
  const int j2 = (colg & 7) * 2;
#pragma unroll
  for (int r = 0; r < 4; ++r) {
    const int m = quad * 4 + r;
    const float4 c = *(const float4*)(cbf + m * 4);
    float y = c.x * (a0[r] + bv[0]) + c.y * (a1[r] + bv[1]) +
              c.z * (a2[r] + bv[2]) + c.w * (a3[r] + bv[3]);
    float a = y > 0.0f ? y : (__expf(y) - 1.0f);  // ELU
    *(unsigned short*)(outBuf + m * 512 + (((g ^ (m & 15)) << 4) + j2)) = f2bf(a);
  }
}

// load one packed K=32 chunk (4 anchors x 1KB contiguous) into rotating slot.
// sb already includes lane*8 shorts; wave-level each load = 1KB linear.
#define LOADCH(sb, ci, sl) do {                                        \
    pre[sl][0] = *(const bf16x8*)((sb) + (ci) * 2048);                 \
    pre[sl][1] = *(const bf16x8*)((sb) + (ci) * 2048 + 512);           \
    pre[sl][2] = *(const bf16x8*)((sb) + (ci) * 2048 + 1024);          \
    pre[sl][3] = *(const bf16x8*)((sb) + (ci) * 2048 + 1536);          \
  } while (0)

// global chunk id c: 0..3 = L0, 4..11 = L1, 12..15 = L2; c>=16 folds to nop
#define ISSUE(c, sl) do {                                              \
    if ((c) < 4)       LOADCH(sb0, (c), sl);                           \
    else if ((c) < 12) LOADCH(sb1, (c) - 4, sl);                       \
    else if ((c) < 16) LOADCH(sb2, (c) - 12, sl);                      \
  } while (0)

#define MFMA4()                                                            \
  acc0 = __builtin_amdgcn_mfma_f32_16x16x32_bf16(av, bv0, acc0, 0, 0, 0);  \
  acc1 = __builtin_amdgcn_mfma_f32_16x16x32_bf16(av, bv1, acc1, 0, 0, 0);  \
  acc2 = __builtin_amdgcn_mfma_f32_16x16x32_bf16(av, bv2, acc2, 0, 0, 0);  \
  acc3 = __builtin_amdgcn_mfma_f32_16x16x32_bf16(av, bv3, acc3, 0, 0, 0)

__global__ __launch_bounds__(1024, 4) void k_fused(
    const float* __restrict__ x, const float* __restrict__ phase,
    const unsigned short* __restrict__ Wt0, const float* __restrict__ b0,
    const unsigned short* __restrict__ Wt1, const float* __restrict__ b1,
    const unsigned short* __restrict__ Wt2, const float* __restrict__ b2,
    float* __restrict__ out) {
  __shared__ __align__(1024) char smem[LDS_TOT];

  const int tid = threadIdx.x;
  const int lane = tid & 63;
  const int wid = tid >> 6;     // 0..15
  const int col = lane & 15;    // MFMA row-of-A / col-of-B lane index
  const int quad = lane >> 4;
  const int m0 = blockIdx.x * 16;
  const int colg = wid * 16 + col;           // L0/L1 output column
  const int cg = wid & 7, kh = wid >> 3;     // L2: col-group + K-half
  const int colg2 = cg * 16 + col;
  const int hi16 = (col & 12) << 4;          // A-swizzle high bits
  const int lb = (quad ^ (col & 3)) << 4;    // A-swizzle low bits

  float* cbf = (float*)(smem + LDS_CB);

  // ---- FIRST loads: cooperative XCD-local L2 prefill (disjoint 32KB/peer).
  //      Issued before everything so their (free) wait lands after layer 0.
  unsigned int ptv;
  {
    const char* wb = (const char*)Wt0 + ((size_t)(blockIdx.x >> 3) << 15) + tid * 32;
    ptv = *(const unsigned int*)wb;
  }

  // packed per-lane source bases (shorts): base + lane*8
  const unsigned short* sb0 = Wt0 + (size_t)wid * 8192 + lane * 8;
  const unsigned short* sb1 = Wt1 + (size_t)wid * 16384 + lane * 8;
  const unsigned short* sb2 = Wt2 + (size_t)(cg * 2 + kh) * 8192 + lane * 8;

  // ---- prologue global loads ----
  float4 xv = {0.f, 0.f, 0.f, 0.f};
  if (tid < 512)
    xv = *(const float4*)(x + (size_t)(m0 + (tid >> 5)) * 128 + (tid & 31) * 4);

  float bva[4], bvb[4], bvc[4];
#pragma unroll
  for (int k = 0; k < 4; ++k) {
    bva[k] = b0[k * 256 + colg];
    bvb[k] = b1[k * 256 + colg];
    bvc[k] = b2[k * 128 + colg2];
  }

  // ---- start the register B pipeline: chunks 0..2 -> slots 0..2 ----
  bf16x8 pre[3][4];
  LOADCH(sb0, 0, 0);
  LOADCH(sb0, 1, 1);
  LOADCH(sb0, 2, 2);

  // Catmull coeff table (16 rows)
  if (tid < 16) {
    float c[4];
    catmull(phase[m0 + tid], c);
    cbf[tid * 4 + 0] = c[0]; cbf[tid * 4 + 1] = c[1];
    cbf[tid * 4 + 2] = c[2]; cbf[tid * 4 + 3] = c[3];
  }

  // ---- build A0: unscaled bf16 x, granule-swizzled (g ^ (row&15)) ----
  if (tid < 512) {
    const int row = tid >> 5, seg = tid & 31;
    const int g = seg >> 1, h = seg & 1;
    short4 hv;
    hv.x = (short)f2bf(xv.x); hv.y = (short)f2bf(xv.y);
    hv.z = (short)f2bf(xv.z); hv.w = (short)f2bf(xv.w);
    *(short4*)(smem + LDS_A0 + row * 256 + ((g ^ (row & 15)) << 4) + h * 8) = hv;
  }
  bar_lgkm();

  f32x4 acc0, acc1, acc2, acc3;

  // ---- layer 0: A0 (K=128 x 4 anchors) @ Wt0 -> A1. steps s=0..3 ----
  {
    acc0 = acc1 = acc2 = acc3 = (f32x4){0.f, 0.f, 0.f, 0.f};
    const char* aL = smem + LDS_A0 + col * 256 + lb;
#pragma unroll
    for (int i = 0; i < 4; ++i) {
      const int sl = i % 3;
      bf16x8 bv0 = pre[sl][0], bv1 = pre[sl][1],
             bv2 = pre[sl][2], bv3 = pre[sl][3];
      ISSUE(i + 3, sl);
      bf16x8 av = *(const bf16x8*)(aL + ((i << 6) ^ hi16));
      MFMA4();
    }
    epi_mid(acc0, acc1, acc2, acc3, bva, cbf, colg, quad, smem + LDS_A1);
  }
  // keep the prefill loads alive (no-op consume; wait here is free: they
  // were the first issued loads and completed long ago)
  asm volatile("" :: "v"(ptv));
  bar_lgkm();

  // ---- layer 1: A1 (K=256 x 4 anchors) @ Wt1 -> A2. steps s=4..11 ----
  {
    acc0 = acc1 = acc2 = acc3 = (f32x4){0.f, 0.f, 0.f, 0.f};
    const char* aL = smem + LDS_A1 + col * 512 + lb;
#pragma unroll
    for (int i = 0; i < 8; ++i) {
      const int s = i + 4;
      const int sl = s % 3;
      bf16x8 bv0 = pre[sl][0], bv1 = pre[sl][1],
             bv2 = pre[sl][2], bv3 = pre[sl][3];
      ISSUE(s + 3, sl);
      bf16x8 av = *(const bf16x8*)(aL + ((i << 6) ^ hi16));
      MFMA4();
    }
    epi_mid(acc0, acc1, acc2, acc3, bvb, cbf, colg, quad, smem + LDS_A2);
  }
  bar_lgkm();

  // ---- layer 2: A2 (K=256 x 4 anchors) @ Wt2 -> out. steps s=12..15 ----
  {
    acc0 = acc1 = acc2 = acc3 = (f32x4){0.f, 0.f, 0.f, 0.f};
    const char* aL = smem + LDS_A2 + col * 512 + kh * 256 + lb;
#pragma unroll
    for (int i = 0; i < 4; ++i) {
      const int s = i + 12;
      const int sl = s % 3;
      bf16x8 bv0 = pre[sl][0], bv1 = pre[sl][1],
             bv2 = pre[sl][2], bv3 = pre[sl][3];
      ISSUE(s + 3, sl);    // s+3 = 15 only at i=0; guards fold away the rest
      bf16x8 av = *(const bf16x8*)(aL + ((i << 6) ^ hi16));
      MFMA4();
    }

    // anchor-combine partials
    float part[4];
#pragma unroll
    for (int r = 0; r < 4; ++r) {
      const int m = quad * 4 + r;
      const float4 c = *(const float4*)(cbf + m * 4);
      part[r] = c.x * acc0[r] + c.y * acc1[r] + c.z * acc2[r] + c.w * acc3[r];
    }

    float* red = (float*)(smem + LDS_RED);   // [8][16][17]
    if (kh) {
#pragma unroll
      for (int r = 0; r < 4; ++r)
        red[cg * 272 + (quad * 4 + r) * 17 + col] = part[r];
    }
    bar_lgkm();
    if (!kh) {
#pragma unroll
      for (int r = 0; r < 4; ++r) {
        const int m = quad * 4 + r;
        const float4 c = *(const float4*)(cbf + m * 4);
        float y = part[r] + red[cg * 272 + m * 17 + col] +
                  c.x * bvc[0] + c.y * bvc[1] + c.z * bvc[2] + c.w * bvc[3];
        out[(size_t)(m0 + m) * 128 + colg2] = y;
      }
    }
  }
}

// ---------------------------------------------------------------------------
// ws layout: Wt0 @0 (256KB), Wt1 @256KB (512KB), Wt2 @768KB (256KB). 1 MB
// contiguous -> the 32 x 32KB prefill slices cover it exactly.
// ---------------------------------------------------------------------------
extern "C" void kernel_launch(void* const* d_in, const int* in_sizes, int n_in,
                              void* d_out, int out_size, void* d_ws, size_t ws_size,
                              hipStream_t stream) {
  const float* x     = (const float*)d_in[0];
  const float* phase = (const float*)d_in[1];
  const float* w0    = (const float*)d_in[2];
  const float* b0    = (const float*)d_in[3];
  const float* w1    = (const float*)d_in[4];
  const float* b1    = (const float*)d_in[5];
  const float* w2    = (const float*)d_in[6];
  const float* b2    = (const float*)d_in[7];
  float* out = (float*)d_out;

  char* ws = (char*)d_ws;
  unsigned short* Wt0 = (unsigned short*)ws;
  unsigned short* Wt1 = (unsigned short*)(ws + 262144);
  unsigned short* Wt2 = (unsigned short*)(ws + 262144 + 524288);

  k_pack<<<64, 256, 0, stream>>>(w0, w1, w2, Wt0, Wt1, Wt2);
  k_fused<<<256, 1024, 0, stream>>>(x, phase, Wt0, b0, Wt1, b1, Wt2, b2, out);
}